// Round 1
// baseline (516.217 us; speedup 1.0000x reference)
//
#include <hip/hip_runtime.h>
#include <hip/hip_cooperative_groups.h>
#include <math.h>

namespace cg = cooperative_groups;

// Problem constants
#define BATCH 64
#define NPTS  2048
// ws float offsets (total 176256 floats = 706 KB)
#define OFF_M   0        // [64][61]  M[b][c*6+a], Sdw at [b][60]
#define OFF_T2  4096     // [64][18]  T2[m][a*3+j]
#define OFF_V   8192     // [384][128] V[ma][v]
#define OFF_D2  57344    // [64][256]
#define OFF_Z   73728    // [64][128]
#define OFF_C2  81920    // [64][64]  center2[b][m]
#define OFF_U2  86016    // [384][64] U2[ma][b]
#define OFF_GP  110592   // [512][128] per-block bn3 partials
#define OFF_SO  176128   // [128] scale[64], offset[64]

// One cooperative kernel. 512 blocks x 256 threads, 2 blocks/CU
// (LDS 62.7KB -> 160/62.7 = 2; launch_bounds(256,2) caps VGPR <= 256).
// Phases separated by grid.sync(); all phase bodies are numerically
// identical to the 9-kernel version (same fma chains, same orders).
__global__ __launch_bounds__(256, 2) void k_all(
    const float* __restrict__ x,
    const float* __restrict__ Wdir,
    const float* __restrict__ g1,
    const float* __restrict__ b1,
    const float* __restrict__ Wdir2,
    const float* __restrict__ g2,
    const float* __restrict__ b2,
    const float* __restrict__ Wf1,
    const float* __restrict__ bf1,
    const float* __restrict__ Wcm,
    const float* __restrict__ bcm,
    const float* __restrict__ Wdc,
    const float* __restrict__ Wm0,
    const float* __restrict__ g3,
    const float* __restrict__ b3,
    const float* __restrict__ Wf2,
    const float* __restrict__ bf2,
    float* __restrict__ ws,
    float* __restrict__ out)
{
    __shared__ __attribute__((aligned(16))) float lds[15677];  // 62.7 KB union
    cg::grid_group grid = cg::this_grid();
    const int blk = blockIdx.x;
    const int t = threadIdx.x;

    // ================= Phase 1: W2 (blocks 0..196)  ||  A (blocks 197..260)
    if (blk < 197) {
        // Fold Wm0 through Wdc: T2 and V
        int idx = blk * 256 + t;
        if (idx < 384 * 128) {
            int ma = idx >> 7, v = idx & 127;
            int a = ma % 6;
            const float* wm = Wm0 + (ma / 6) * 256;
            float s = 0.f;
#pragma unroll 8
            for (int e = 0; e < 256; ++e)
                s = fmaf(wm[e], Wdc[(e * 6 + a) * 131 + 3 + v], s);
            ws[OFF_V + ma * 128 + v] = s;
        } else if (idx < 384 * 128 + 64 * 18) {
            int j2 = idx - 384 * 128;
            int m = j2 / 18, r = j2 % 18;
            int a = r / 3, j = r % 3;
            const float* wm = Wm0 + m * 256;
            float s = 0.f;
#pragma unroll 8
            for (int e = 0; e < 256; ++e)
                s = fmaf(wm[e], Wdc[(e * 6 + a) * 131 + j], s);
            ws[OFF_T2 + m * 18 + r] = s;
        }
    } else if (blk < 261) {
        // Stage A: per-batch moments for aggregate()
        int b = blk - 197;
        float* red = lds;                       // [61][257]
        float acc[61];
#pragma unroll
        for (int i = 0; i < 61; ++i) acc[i] = 0.f;
        for (int k = 0; k < 8; ++k) {
            int n = t + 256 * k;
            const float* xp = x + (size_t)(b * NPTS + n) * 10;
            float xv[10];
#pragma unroll
            for (int j = 0; j < 5; ++j) {
                float2 v = *(const float2*)(xp + 2 * j);
                xv[2 * j] = v.x; xv[2 * j + 1] = v.y;
            }
            float x0 = xv[0], x1 = xv[1], x2 = xv[2];
            float rn = x0 * x0 + x1 * x1 + x2 * x2;
            float norm = sqrtf(rn);
            float inv = 1.f / (norm + 1e-8f);
            float c2[6];
            c2[0] = fmaxf(x2, 0.f) * inv; c2[1] = fmaxf(-x2, 0.f) * inv;
            c2[2] = fmaxf(x1, 0.f) * inv; c2[3] = fmaxf(-x1, 0.f) * inv;
            c2[4] = fmaxf(x0, 0.f) * inv; c2[5] = fmaxf(-x0, 0.f) * inv;
#pragma unroll
            for (int a = 0; a < 6; ++a) c2[a] *= c2[a];
            float dw = 1.f - (rn - 1.f) * (1.f / 3.f);
            if (dw < 0.f) dw = 0.f;
            if (norm <= 0.f) dw = 0.f;
            float cw[6];
#pragma unroll
            for (int a = 0; a < 6; ++a) cw[a] = c2[a] * dw;
#pragma unroll
            for (int c = 0; c < 10; ++c) {
                float dv = (c < 7) ? xv[3 + c] : xv[c - 7];
#pragma unroll
                for (int a = 0; a < 6; ++a)
                    acc[c * 6 + a] = fmaf(dv, cw[a], acc[c * 6 + a]);
            }
            acc[60] += dw;
        }
#pragma unroll
        for (int i = 0; i < 61; ++i) red[i * 257 + t] = acc[i];
        __syncthreads();
        if (t < 61) {
            float s = 0.f;
#pragma unroll 8
            for (int j = 0; j < 256; ++j) s += red[t * 257 + j];
            ws[OFF_M + b * 61 + t] = s;
        }
    }
    grid.sync();

    // ================= Phase 2: B1 (blocks 0..7)
    if (blk < 8) {
        float* Wd  = lds;             // [64][61]
        float* Ml  = lds + 3904;      // [64][61]
        float* h1  = lds + 7808;      // [64][64]
        float* wt2 = lds + 11904;     // [32][65]
        float* sc  = lds + 13984;     // [64]
        float* of  = lds + 14048;     // [64]
        for (int g = t; g < 64 * 61; g += 256) Ml[g] = ws[OFF_M + g];
        for (int g = t; g < 3840; g += 256) Wd[(g / 60) * 61 + g % 60] = Wdir[g];
        {
            const float* src = Wdir2 + blk * 32 * 64;
            for (int g = t; g < 2048; g += 256) wt2[(g >> 6) * 65 + (g & 63)] = src[g];
        }
        __syncthreads();
        int m = t & 63;
        float Wr[60];
#pragma unroll
        for (int r = 0; r < 60; ++r) Wr[r] = Wd[m * 61 + r];
#pragma unroll
        for (int k = 0; k < 16; ++k) {
            int e0 = t + 256 * k;
            int b = e0 >> 6;
            const float* Mb = Ml + b * 61;
            float s = 0.f;
#pragma unroll
            for (int a = 0; a < 6; ++a)
#pragma unroll
                for (int c = 0; c < 10; ++c)
                    s = fmaf(Wr[a * 10 + c], Mb[c * 6 + a], s);
            h1[e0] = s / Mb[60];
        }
        __syncthreads();
        if (t < 64) {
            float s = 0.f, q = 0.f;
#pragma unroll 8
            for (int b = 0; b < 64; ++b) { float v = h1[b * 64 + t]; s += v; q = fmaf(v, v, q); }
            float mean = s * (1.f / 64.f);
            float var = q * (1.f / 64.f) - mean * mean;
            float scale = g1[t] * rsqrtf(var + 1e-5f);
            sc[t] = scale; of[t] = b1[t] - mean * scale;
        }
        __syncthreads();
#pragma unroll
        for (int k = 0; k < 16; ++k) {
            int e0 = t + 256 * k;
            h1[e0] = fmaxf(fmaf(h1[e0], sc[e0 & 63], of[e0 & 63]), 0.f);
        }
        __syncthreads();
        int e_loc = t & 31;
        float wr[64];
#pragma unroll
        for (int mm = 0; mm < 64; ++mm) wr[mm] = wt2[e_loc * 65 + mm];
        int b0 = t >> 5;
        int e = blk * 32 + e_loc;
#pragma unroll
        for (int k = 0; k < 8; ++k) {
            int b = b0 + 8 * k;
            const float* h = h1 + b * 64;
            float s = 0.f;
#pragma unroll
            for (int mm = 0; mm < 64; ++mm) s = fmaf(h[mm], wr[mm], s);
            ws[OFF_D2 + b * 256 + e] = s;
        }
    }
    grid.sync();

    // ================= Phase 3: Z (blocks 0..15), bn2 stats fused (was k_s2)
    if (blk < 16) {
        float* Wl  = lds;             // [32][257]
        float* El  = lds + 8224;      // [16][257]
        float* scl = lds + 12336;     // [256]
        float* ofl = lds + 12592;     // [256]
        int vb = blk >> 2, bb = blk & 3;
        // redundant per-block bn2 stats, column t (identical FP order across blocks)
        {
            float s = 0.f, q = 0.f;
#pragma unroll
            for (int b = 0; b < 64; ++b) {
                float v = ws[OFF_D2 + b * 256 + t];
                s += v; q = fmaf(v, v, q);
            }
            float mean = s * (1.f / 64.f);
            float var = q * (1.f / 64.f) - mean * mean;
            float scale = g2[t] * rsqrtf(var + 1e-5f);
            scl[t] = scale; ofl[t] = b2[t] - mean * scale;
        }
        const float* Wsrc = Wf1 + vb * 32 * 256;
        for (int g = t; g < 32 * 256; g += 256) Wl[(g >> 8) * 257 + (g & 255)] = Wsrc[g];
        __syncthreads();
        const float* Esrc = ws + OFF_D2 + bb * 16 * 256;
        for (int g = t; g < 16 * 256; g += 256) {
            int e = g & 255;
            El[(g >> 8) * 257 + e] = fmaxf(fmaf(Esrc[g], scl[e], ofl[e]), 0.f);
        }
        __syncthreads();
        int v_loc = t & 31, b_loc = t >> 5;
        const float* W  = Wl + v_loc * 257;
        const float* E0 = El + b_loc * 257;
        const float* E1 = El + (b_loc + 8) * 257;
        float s0 = 0.f, s1 = 0.f;
#pragma unroll 8
        for (int e = 0; e < 256; ++e) {
            float w = W[e];
            s0 = fmaf(E0[e], w, s0);
            s1 = fmaf(E1[e], w, s1);
        }
        int v = vb * 32 + v_loc;
        float bias = bf1[v];
        ws[OFF_Z + (bb * 16 + b_loc) * 128 + v] = s0 + bias;
        ws[OFF_Z + (bb * 16 + b_loc + 8) * 128 + v] = s1 + bias;
    }
    grid.sync();

    // ================= Phase 4: U (blocks 0..111)
    if (blk < 112) {
        if (blk < 96) {
            float* zl = lds;                 // [64][129]
            float* Vl = lds + 64 * 129;      // [4][128]
            for (int g = t; g < 8192; g += 256) zl[(g >> 7) * 129 + (g & 127)] = ws[OFF_Z + g];
            const float* Vsrc = ws + OFF_V + blk * 4 * 128;
            for (int g = t; g < 512; g += 256) Vl[g] = Vsrc[g];
            __syncthreads();
            int ma_loc = t >> 6, b = t & 63;
            const float* z = zl + b * 129;
            const float* v = Vl + ma_loc * 128;
            float s = 0.f;
#pragma unroll 8
            for (int i = 0; i < 128; ++i) s = fmaf(z[i], v[i], s);
            ws[OFF_U2 + (blk * 4 + ma_loc) * 64 + b] = s;
        } else {
            float* Wl2 = lds;                    // [64][133]
            float* zl2 = lds + 64 * 133;         // [4][128]
            float* xl  = lds + 64 * 133 + 512;   // [12]
            int b0 = (blk - 96) * 4;
            for (int g = t; g < 64 * 131; g += 256) Wl2[(g / 131) * 133 + g % 131] = Wcm[g];
            for (int g = t; g < 512; g += 256) zl2[g] = ws[OFF_Z + b0 * 128 + g];
            if (t < 12) xl[t] = x[(size_t)(b0 + t / 3) * NPTS * 10 + t % 3];
            __syncthreads();
            int m = t & 63, b_loc = t >> 6;
            const float* w = Wl2 + m * 133;
            const float* z = zl2 + b_loc * 128;
            float s = bcm[m];
#pragma unroll 8
            for (int i = 0; i < 128; ++i) s = fmaf(z[i], w[i], s);
            s = fmaf(xl[b_loc * 3 + 0], w[128], s);
            s = fmaf(xl[b_loc * 3 + 1], w[129], s);
            s = fmaf(xl[b_loc * 3 + 2], w[130], s);
            ws[OFF_C2 + (b0 + b_loc) * 64 + m] = s;
        }
    }
    grid.sync();

    // ================= Phase 5: C (all 512 blocks) — bn3 partials
    {
        float* r2 = lds;                     // [512]
        int b = blk >> 3, c = blk & 7;
        int m = t & 63;
        int g = __builtin_amdgcn_readfirstlane(t >> 6);
        float T[18], U[6];
        const float* t2 = ws + OFF_T2 + m * 18;
#pragma unroll
        for (int r = 0; r < 18; ++r) T[r] = t2[r];
#pragma unroll
        for (int a = 0; a < 6; ++a) U[a] = ws[OFF_U2 + (m * 6 + a) * 64 + b];
        bool has0 = (c == 0) && (g == 0);
        float c2v = 0.f;
        if (has0) c2v = ws[OFF_C2 + b * 64 + m];
        float accS = 0.f, accQ = 0.f;
        int p0 = c * 256 + g * 64;
        const float* xb = x + (size_t)b * NPTS * 10;
#pragma unroll 4
        for (int i = 0; i < 64; ++i) {
            const float* xp = xb + (p0 + i) * 10;
            float x0 = xp[0], x1 = xp[1], x2 = xp[2];
            float rn = x0 * x0 + x1 * x1 + x2 * x2;
            float inv = 1.f / (sqrtf(rn) + 1e-8f);
            float c2[6];
            c2[0] = fmaxf(x2, 0.f) * inv; c2[1] = fmaxf(-x2, 0.f) * inv;
            c2[2] = fmaxf(x1, 0.f) * inv; c2[3] = fmaxf(-x1, 0.f) * inv;
            c2[4] = fmaxf(x0, 0.f) * inv; c2[5] = fmaxf(-x0, 0.f) * inv;
            float h = 0.f;
#pragma unroll
            for (int a = 0; a < 6; ++a) {
                float cc = c2[a] * c2[a];
                float ta = fmaf(x0, T[a * 3], fmaf(x1, T[a * 3 + 1], fmaf(x2, T[a * 3 + 2], U[a])));
                h = fmaf(cc, ta, h);
            }
            if (has0 && i == 0) h = c2v;
            accS += h;
            accQ = fmaf(h, h, accQ);
        }
        r2[t] = accS; r2[256 + t] = accQ;
        __syncthreads();
        if (t < 64) {
            ws[OFF_GP + blk * 128 + t] = r2[t] + r2[64 + t] + r2[128 + t] + r2[192 + t];
        } else if (t < 128) {
            int mm = t - 64;
            ws[OFF_GP + blk * 128 + t] = r2[256 + mm] + r2[320 + mm] + r2[384 + mm] + r2[448 + mm];
        }
    }
    grid.sync();

    // ================= Phase 6: FIN (block 0)
    if (blk == 0) {
        float* r = lds;                      // [512]
        int m = t & 63, g = t >> 6;
        float s = 0.f, q = 0.f;
#pragma unroll 8
        for (int j = 0; j < 128; ++j) {
            int bb = g * 128 + j;
            s += ws[OFF_GP + bb * 128 + m];
            q += ws[OFF_GP + bb * 128 + 64 + m];
        }
        r[t] = s; r[256 + t] = q;
        __syncthreads();
        if (t < 64) {
            float S = r[t] + r[64 + t] + r[128 + t] + r[192 + t];
            float Q = r[256 + t] + r[320 + t] + r[384 + t] + r[448 + t];
            float mean = S * (1.f / 131072.f);
            float var = Q * (1.f / 131072.f) - mean * mean;
            float scale = g3[t] * rsqrtf(var + 1e-5f);
            ws[OFF_SO + t] = scale;
            ws[OFF_SO + 64 + t] = b3[t] - mean * scale;
        }
    }
    grid.sync();

    // ================= Phase 7: E (all 512 blocks) — LDS-fed, coalesced out
    {
        float* Wl24 = lds;          // [64][24]: per-m {T2[a*3+j] at a*4+j, U2 at a*4+3}
        float* Pl   = lds + 1536;   // [64][12]: {Wf2[0..6], scale, off, pad x3}
        float* C2l  = lds + 2304;   // [64]
        float* yout = lds + 2368;   // [1792]
        int b = blk >> 3;
        for (int g = t; g < 1152; g += 256) {
            int m = g / 18, r = g % 18;
            int a = r / 3, j = r % 3;
            Wl24[m * 24 + a * 4 + j] = ws[OFF_T2 + g];
        }
        for (int g = t; g < 384; g += 256)
            Wl24[(g / 6) * 24 + (g % 6) * 4 + 3] = ws[OFF_U2 + g * 64 + b];
        for (int g = t; g < 448; g += 256) {
            int m = g / 7, k = g % 7;
            Pl[m * 12 + k] = Wf2[k * 64 + m];
        }
        if (t < 64) {
            Pl[t * 12 + 7] = ws[OFF_SO + t];
            Pl[t * 12 + 8] = ws[OFF_SO + 64 + t];
        }
        if (((blk & 7) == 0) && t < 64) C2l[t] = ws[OFF_C2 + b * 64 + t];
        __syncthreads();

        int idx = blk * 256 + t;
        const float* xp = x + (size_t)idx * 10;
        float x0 = xp[0], x1 = xp[1], x2 = xp[2];
        float rn = x0 * x0 + x1 * x1 + x2 * x2;
        float inv = 1.f / (sqrtf(rn) + 1e-8f);
        float c2[6];
        c2[0] = fmaxf(x2, 0.f) * inv; c2[1] = fmaxf(-x2, 0.f) * inv;
        c2[2] = fmaxf(x1, 0.f) * inv; c2[3] = fmaxf(-x1, 0.f) * inv;
        c2[4] = fmaxf(x0, 0.f) * inv; c2[5] = fmaxf(-x0, 0.f) * inv;
#pragma unroll
        for (int a = 0; a < 6; ++a) c2[a] *= c2[a];
        bool c0 = ((idx & 2047) == 0);
        float y[7];
#pragma unroll
        for (int k = 0; k < 7; ++k) y[k] = bf2[k];
#pragma unroll 4
        for (int m = 0; m < 64; ++m) {
            const float4* Wm = (const float4*)(Wl24 + m * 24);
            float h = 0.f;
#pragma unroll
            for (int a = 0; a < 6; ++a) {
                float4 wq = Wm[a];   // {T0,T1,T2,U}
                float ta = fmaf(x0, wq.x, fmaf(x1, wq.y, fmaf(x2, wq.z, wq.w)));
                h = fmaf(c2[a], ta, h);
            }
            if (c0) h = C2l[m];
            const float4* Pm = (const float4*)(Pl + m * 12);
            float4 p0 = Pm[0], p1 = Pm[1];
            float offv = Pl[m * 12 + 8];
            float r = fmaxf(fmaf(h, p1.w, offv), 0.f);
            y[0] = fmaf(r, p0.x, y[0]); y[1] = fmaf(r, p0.y, y[1]);
            y[2] = fmaf(r, p0.z, y[2]); y[3] = fmaf(r, p0.w, y[3]);
            y[4] = fmaf(r, p1.x, y[4]); y[5] = fmaf(r, p1.y, y[5]);
            y[6] = fmaf(r, p1.z, y[6]);
        }
#pragma unroll
        for (int k = 0; k < 7; ++k) yout[t * 7 + k] = 1.f / (1.f + __expf(-y[k]));
        __syncthreads();
        float* op = out + (size_t)blk * 1792;
        for (int g = t; g < 1792; g += 256) op[g] = yout[g];
    }
}

// ---------------------------------------------------------------------------
extern "C" void kernel_launch(void* const* d_in, const int* in_sizes, int n_in,
                              void* d_out, int out_size, void* d_ws, size_t ws_size,
                              hipStream_t stream) {
    const float* x     = (const float*)d_in[0];
    // d_in[1]=Wc, d_in[2]=bc : dead code in reference (center is unused)
    const float* Wdir  = (const float*)d_in[3];
    const float* g1    = (const float*)d_in[4];
    const float* b1    = (const float*)d_in[5];
    const float* Wdir2 = (const float*)d_in[6];
    const float* g2    = (const float*)d_in[7];
    const float* b2    = (const float*)d_in[8];
    const float* Wf1   = (const float*)d_in[9];
    const float* bf1   = (const float*)d_in[10];
    const float* Wcm   = (const float*)d_in[11];
    const float* bcm   = (const float*)d_in[12];
    const float* Wdc   = (const float*)d_in[13];
    const float* Wm0   = (const float*)d_in[14];
    const float* g3    = (const float*)d_in[15];
    const float* b3    = (const float*)d_in[16];
    const float* Wf2   = (const float*)d_in[17];
    const float* bf2   = (const float*)d_in[18];
    float* ws  = (float*)d_ws;
    float* out = (float*)d_out;

    void* args[] = {
        (void*)&x, (void*)&Wdir, (void*)&g1, (void*)&b1, (void*)&Wdir2,
        (void*)&g2, (void*)&b2, (void*)&Wf1, (void*)&bf1, (void*)&Wcm,
        (void*)&bcm, (void*)&Wdc, (void*)&Wm0, (void*)&g3, (void*)&b3,
        (void*)&Wf2, (void*)&bf2, (void*)&ws, (void*)&out
    };
    hipLaunchCooperativeKernel((const void*)k_all, dim3(512), dim3(256),
                               args, 0, stream);
}

// Round 2
// 200.583 us; speedup vs baseline: 2.5736x; 2.5736x over previous
//
#include <hip/hip_runtime.h>
#include <math.h>

// Problem constants
#define BATCH 64
#define NPTS  2048
// ws float offsets
#define OFF_M   0        // [64][61]  M[b][c*6+a], Sdw at [b][60]
#define OFF_T2  4096     // [64][18]  T2[m][a*3+j]
#define OFF_V   8192     // TRANSPOSED: Vt[v][ma] = [128][384]
#define OFF_Z   73728    // [64][128] z (bias-init + atomic partials)
#define OFF_GP  110592   // [512][128] per-block bn3 partials
#define OFF_SO  176128   // [128] scale[64], offset[64]

// ---------------------------------------------------------------------------
// k_wa: (blocks 0..196) fold Wm0 through Wdc -> T2, Vt(transposed)
//       (blocks 197..260) stage-A per-batch moments
//       (block 261) init Z with bf1 bias (atomic partials land on top)
__global__ __launch_bounds__(256) void k_wa(const float* __restrict__ x,
                                            const float* __restrict__ Wm0,
                                            const float* __restrict__ Wdc,
                                            const float* __restrict__ bf1,
                                            float* __restrict__ ws) {
    __shared__ float red[61 * 257];
    int blk = blockIdx.x, t = threadIdx.x;
    if (blk < 197) {
        int idx = blk * 256 + t;
        if (idx < 384 * 128) {
            int ma = idx >> 7, v = idx & 127;
            int a = ma % 6;
            const float* wm = Wm0 + (ma / 6) * 256;   // wave-uniform -> s_load
            float s = 0.f;
#pragma unroll 8
            for (int e = 0; e < 256; ++e)
                s = fmaf(wm[e], Wdc[(e * 6 + a) * 131 + 3 + v], s);
            ws[OFF_V + v * 384 + ma] = s;             // transposed store
        } else if (idx < 384 * 128 + 64 * 18) {
            int j2 = idx - 384 * 128;
            int m = j2 / 18, r = j2 % 18;
            int a = r / 3, j = r % 3;
            const float* wm = Wm0 + m * 256;
            float s = 0.f;
#pragma unroll 8
            for (int e = 0; e < 256; ++e)
                s = fmaf(wm[e], Wdc[(e * 6 + a) * 131 + j], s);
            ws[OFF_T2 + m * 18 + r] = s;
        }
    } else if (blk < 261) {
        int b = blk - 197;
        float acc[61];
#pragma unroll
        for (int i = 0; i < 61; ++i) acc[i] = 0.f;
        for (int k = 0; k < 8; ++k) {
            int n = t + 256 * k;
            const float* xp = x + (size_t)(b * NPTS + n) * 10;
            float xv[10];
#pragma unroll
            for (int j = 0; j < 5; ++j) {
                float2 v = *(const float2*)(xp + 2 * j);
                xv[2 * j] = v.x; xv[2 * j + 1] = v.y;
            }
            float x0 = xv[0], x1 = xv[1], x2 = xv[2];
            float rn = x0 * x0 + x1 * x1 + x2 * x2;
            float norm = sqrtf(rn);
            float inv = 1.f / (norm + 1e-8f);
            float c2[6];
            c2[0] = fmaxf(x2, 0.f) * inv; c2[1] = fmaxf(-x2, 0.f) * inv;
            c2[2] = fmaxf(x1, 0.f) * inv; c2[3] = fmaxf(-x1, 0.f) * inv;
            c2[4] = fmaxf(x0, 0.f) * inv; c2[5] = fmaxf(-x0, 0.f) * inv;
#pragma unroll
            for (int a = 0; a < 6; ++a) c2[a] *= c2[a];
            float dw = 1.f - (rn - 1.f) * (1.f / 3.f);
            if (dw < 0.f) dw = 0.f;
            if (norm <= 0.f) dw = 0.f;
            float cw[6];
#pragma unroll
            for (int a = 0; a < 6; ++a) cw[a] = c2[a] * dw;
#pragma unroll
            for (int c = 0; c < 10; ++c) {
                float dv = (c < 7) ? xv[3 + c] : xv[c - 7];
#pragma unroll
                for (int a = 0; a < 6; ++a)
                    acc[c * 6 + a] = fmaf(dv, cw[a], acc[c * 6 + a]);
            }
            acc[60] += dw;
        }
#pragma unroll
        for (int i = 0; i < 61; ++i) red[i * 257 + t] = acc[i];
        __syncthreads();
        if (t < 61) {
            float s = 0.f;
#pragma unroll 8
            for (int j = 0; j < 256; ++j) s += red[t * 257 + j];
            ws[OFF_M + b * 61 + t] = s;
        }
    } else {
        // init Z with bias
        for (int g = t; g < 64 * 128; g += 256) ws[OFF_Z + g] = bf1[g & 127];
    }
}

// ---------------------------------------------------------------------------
// k_b1z: b1 + bn2 + z fused. 8 blocks; block owns e-columns [32*blk, 32*blk+32).
// D2 stays in LDS (bn2 is block-local over the batch dim); z accumulated via
// atomicAdd partials (sum over this block's 32 e-columns).
__global__ __launch_bounds__(256) void k_b1z(const float* __restrict__ Wdir,
                                             const float* __restrict__ g1,
                                             const float* __restrict__ b1,
                                             const float* __restrict__ Wdir2,
                                             const float* __restrict__ g2,
                                             const float* __restrict__ b2,
                                             const float* __restrict__ Wf1,
                                             float* __restrict__ ws) {
    __shared__ float L[14496];
    float* Wd  = L;            // [64][61]; reused as D2l [64][33] after S2
    float* D2l = L;            // alias (written post-S4, Wd dead after S2)
    float* Ml  = L + 3904;     // [64][61]; reused as wfl [128][33] after S5
    float* wfl = L + 3904;     // alias
    float* h1  = L + 8128;     // [64][64]
    float* wt2 = L + 12224;    // [32][65]
    float* sc  = L + 14304;    // [64]
    float* of  = L + 14368;    // [64]
    float* scl = L + 14432;    // [32]
    float* ofl = L + 14464;    // [32]
    int blk = blockIdx.x, t = threadIdx.x;
    for (int g = t; g < 64 * 61; g += 256) Ml[g] = ws[OFF_M + g];
    for (int g = t; g < 3840; g += 256) Wd[(g / 60) * 61 + g % 60] = Wdir[g];
    {
        const float* src = Wdir2 + blk * 32 * 64;
        for (int g = t; g < 2048; g += 256) wt2[(g >> 6) * 65 + (g & 63)] = src[g];
    }
    __syncthreads();                              // S1
    int m = t & 63;
    float Wr[60];
#pragma unroll
    for (int r = 0; r < 60; ++r) Wr[r] = Wd[m * 61 + r];
#pragma unroll
    for (int k = 0; k < 16; ++k) {
        int e0 = t + 256 * k;
        int b = e0 >> 6;
        const float* Mb = Ml + b * 61;
        float s = 0.f;
#pragma unroll
        for (int a = 0; a < 6; ++a)
#pragma unroll
            for (int c = 0; c < 10; ++c)
                s = fmaf(Wr[a * 10 + c], Mb[c * 6 + a], s);
        h1[e0] = s / Mb[60];
    }
    __syncthreads();                              // S2
    if (t < 64) {
        float s = 0.f, q = 0.f;
#pragma unroll 8
        for (int b = 0; b < 64; ++b) { float v = h1[b * 64 + t]; s += v; q = fmaf(v, v, q); }
        float mean = s * (1.f / 64.f);
        float var = q * (1.f / 64.f) - mean * mean;
        float scale = g1[t] * rsqrtf(var + 1e-5f);
        sc[t] = scale; of[t] = b1[t] - mean * scale;
    }
    __syncthreads();                              // S3
#pragma unroll
    for (int k = 0; k < 16; ++k) {
        int e0 = t + 256 * k;
        h1[e0] = fmaxf(fmaf(h1[e0], sc[e0 & 63], of[e0 & 63]), 0.f);
    }
    __syncthreads();                              // S4
    // d2 for this block's 32 e-columns, all 64 batches -> LDS (Wd region, dead)
    {
        int e_loc = t & 31;
        float wr[64];
#pragma unroll
        for (int mm = 0; mm < 64; ++mm) wr[mm] = wt2[e_loc * 65 + mm];
        int b0 = t >> 5;
#pragma unroll
        for (int k = 0; k < 8; ++k) {
            int b = b0 + 8 * k;
            const float* h = h1 + b * 64;
            float s = 0.f;
#pragma unroll
            for (int mm = 0; mm < 64; ++mm) s = fmaf(h[mm], wr[mm], s);
            D2l[b * 33 + e_loc] = s;
        }
    }
    __syncthreads();                              // S5
    // stage Wf1 tile [128 v][32 e] (Ml region, dead) ; bn2 stats (block-local)
    for (int g = t; g < 128 * 32; g += 256)
        wfl[(g >> 5) * 33 + (g & 31)] = Wf1[(g >> 5) * 256 + blk * 32 + (g & 31)];
    if (t < 32) {
        float s = 0.f, q = 0.f;
#pragma unroll
        for (int b = 0; b < 64; ++b) { float v = D2l[b * 33 + t]; s += v; q = fmaf(v, v, q); }
        float mean = s * (1.f / 64.f);
        float var = q * (1.f / 64.f) - mean * mean;
        int E = blk * 32 + t;
        float scale = g2[E] * rsqrtf(var + 1e-5f);
        scl[t] = scale; ofl[t] = b2[E] - mean * scale;
    }
    __syncthreads();                              // S6
    for (int g = t; g < 2048; g += 256) {
        int b = g >> 5, e = g & 31;
        D2l[b * 33 + e] = fmaxf(fmaf(D2l[b * 33 + e], scl[e], ofl[e]), 0.f);
    }
    __syncthreads();                              // S7
    // z partials: thread owns v = t&127, 32 batches; sum over 32 local e
    {
        int v = t & 127, half = t >> 7;
        float wv[32];
#pragma unroll
        for (int e = 0; e < 32; ++e) wv[e] = wfl[v * 33 + e];
#pragma unroll
        for (int j = 0; j < 32; ++j) {
            int b = half * 32 + j;
            const float* d = D2l + b * 33;        // wave-uniform -> broadcast
            float s = 0.f;
#pragma unroll
            for (int e = 0; e < 32; ++e) s = fmaf(d[e], wv[e], s);
            atomicAdd(&ws[OFF_Z + b * 128 + v], s);
        }
    }
}

// ---------------------------------------------------------------------------
// k_c: bn3 partials. U2/C2 recomputed per block (cheap; k_u eliminated).
__global__ __launch_bounds__(256) void k_c(const float* __restrict__ x,
                                           const float* __restrict__ Wcm,
                                           const float* __restrict__ bcm,
                                           float* __restrict__ ws) {
    __shared__ float L[10560];
    float* zl  = L;            // [128]
    float* T2l = L + 128;      // [1152]
    float* U2l = L + 1280;     // [384]
    float* r2  = L + 1664;     // [512]
    float* wcm = L + 2176;     // [64*131] only staged when c==0
    int blk = blockIdx.x, t = threadIdx.x;
    int b = blk >> 3, c = blk & 7;
    if (t < 128) zl[t] = ws[OFF_Z + b * 128 + t];
    for (int g = t; g < 1152; g += 256) T2l[g] = ws[OFF_T2 + g];
    if (c == 0)
        for (int g = t; g < 64 * 131; g += 256) wcm[g] = Wcm[g];
    __syncthreads();
    // U2[ma][b] recompute: thread t -> ma = t (and t+256), coalesced Vt reads
    {
        const float* Vt = ws + OFF_V;
        float s0 = 0.f;
#pragma unroll 8
        for (int v = 0; v < 128; ++v) s0 = fmaf(zl[v], Vt[v * 384 + t], s0);
        U2l[t] = s0;
        if (t < 128) {
            float s1 = 0.f;
#pragma unroll 8
            for (int v = 0; v < 128; ++v) s1 = fmaf(zl[v], Vt[v * 384 + 256 + t], s1);
            U2l[256 + t] = s1;
        }
    }
    // C2[b][m] recompute for has0 threads only (m = t < 64), same order as old k_u
    float c2v = 0.f;
    bool has0 = (c == 0) && (t < 64);
    if (has0) {
        const float* w = wcm + t * 131;
        float s = bcm[t];
#pragma unroll 8
        for (int i = 0; i < 128; ++i) s = fmaf(zl[i], w[i], s);
        s = fmaf(x[(size_t)b * NPTS * 10 + 0], w[128], s);
        s = fmaf(x[(size_t)b * NPTS * 10 + 1], w[129], s);
        s = fmaf(x[(size_t)b * NPTS * 10 + 2], w[130], s);
        c2v = s;
    }
    __syncthreads();
    int m = t & 63;
    int g = __builtin_amdgcn_readfirstlane(t >> 6);
    float T[18], U[6];
#pragma unroll
    for (int r = 0; r < 18; ++r) T[r] = T2l[m * 18 + r];
#pragma unroll
    for (int a = 0; a < 6; ++a) U[a] = U2l[m * 6 + a];
    float accS = 0.f, accQ = 0.f;
    int p0 = c * 256 + g * 64;
    const float* xb = x + (size_t)b * NPTS * 10;
#pragma unroll 4
    for (int i = 0; i < 64; ++i) {
        const float* xp = xb + (p0 + i) * 10;     // wave-uniform address
        float x0 = xp[0], x1 = xp[1], x2 = xp[2];
        float rn = x0 * x0 + x1 * x1 + x2 * x2;
        float inv = 1.f / (sqrtf(rn) + 1e-8f);
        float c2[6];
        c2[0] = fmaxf(x2, 0.f) * inv; c2[1] = fmaxf(-x2, 0.f) * inv;
        c2[2] = fmaxf(x1, 0.f) * inv; c2[3] = fmaxf(-x1, 0.f) * inv;
        c2[4] = fmaxf(x0, 0.f) * inv; c2[5] = fmaxf(-x0, 0.f) * inv;
        float h = 0.f;
#pragma unroll
        for (int a = 0; a < 6; ++a) {
            float cc = c2[a] * c2[a];
            float ta = fmaf(x0, T[a * 3], fmaf(x1, T[a * 3 + 1], fmaf(x2, T[a * 3 + 2], U[a])));
            h = fmaf(cc, ta, h);
        }
        if (has0 && i == 0) h = c2v;              // g==0 is implied by t<64
        accS += h;
        accQ = fmaf(h, h, accQ);
    }
    r2[t] = accS; r2[256 + t] = accQ;
    __syncthreads();
    if (t < 64) {
        ws[OFF_GP + blk * 128 + t] = r2[t] + r2[64 + t] + r2[128 + t] + r2[192 + t];
    } else if (t < 128) {
        int mm = t - 64;
        ws[OFF_GP + blk * 128 + t] = r2[256 + mm] + r2[320 + mm] + r2[384 + mm] + r2[448 + mm];
    }
}

// ---------------------------------------------------------------------------
__global__ __launch_bounds__(256) void k_fin(const float* __restrict__ g3,
                                             const float* __restrict__ b3,
                                             float* __restrict__ ws) {
    __shared__ float r[512];
    int t = threadIdx.x;
    int m = t & 63, g = t >> 6;
    float s = 0.f, q = 0.f;
#pragma unroll 8
    for (int j = 0; j < 128; ++j) {
        int blk = g * 128 + j;
        s += ws[OFF_GP + blk * 128 + m];
        q += ws[OFF_GP + blk * 128 + 64 + m];
    }
    r[t] = s; r[256 + t] = q;
    __syncthreads();
    if (t < 64) {
        float S = r[t] + r[64 + t] + r[128 + t] + r[192 + t];
        float Q = r[256 + t] + r[320 + t] + r[384 + t] + r[448 + t];
        float mean = S * (1.f / 131072.f);
        float var = Q * (1.f / 131072.f) - mean * mean;
        float scale = g3[t] * rsqrtf(var + 1e-5f);
        ws[OFF_SO + t] = scale;
        ws[OFF_SO + 64 + t] = b3[t] - mean * scale;
    }
}

// ---------------------------------------------------------------------------
// k_e: LDS-fed epilogue; U2/C2 recomputed per block; coalesced output.
__global__ __launch_bounds__(256) void k_e(const float* __restrict__ x,
                                           const float* __restrict__ Wcm,
                                           const float* __restrict__ bcm,
                                           const float* __restrict__ Wf2,
                                           const float* __restrict__ bf2,
                                           const float* __restrict__ ws,
                                           float* __restrict__ out) {
    __shared__ float L[10880];
    float* zl   = L;           // [128]
    float* Wl24 = L + 128;     // [64][24]: {T2[a*3+j] at a*4+j, U2 at a*4+3}
    float* Pl   = L + 1664;    // [64][12]: {Wf2[0..6], scale, off}
    float* C2l  = L + 2432;    // [64]
    float* wcm  = L + 2496;    // [64*131] (union with yout; used pre-main-loop)
    float* yout = L + 2496;    // [1792]
    int blk = blockIdx.x, t = threadIdx.x;
    int b = blk >> 3;
    bool first = (blk & 7) == 0;
    if (t < 128) zl[t] = ws[OFF_Z + b * 128 + t];
    for (int g = t; g < 1152; g += 256) {
        int m = g / 18, r = g % 18;
        int a = r / 3, j = r % 3;
        Wl24[m * 24 + a * 4 + j] = ws[OFF_T2 + g];
    }
    for (int g = t; g < 448; g += 256) {
        int m = g / 7, k = g % 7;
        Pl[m * 12 + k] = Wf2[k * 64 + m];
    }
    if (t < 64) {
        Pl[t * 12 + 7] = ws[OFF_SO + t];
        Pl[t * 12 + 8] = ws[OFF_SO + 64 + t];
    }
    if (first)
        for (int g = t; g < 64 * 131; g += 256) wcm[g] = Wcm[g];
    __syncthreads();
    // U2 recompute into Wl24 slots (same order as k_c)
    {
        const float* Vt = ws + OFF_V;
        float s0 = 0.f;
#pragma unroll 8
        for (int v = 0; v < 128; ++v) s0 = fmaf(zl[v], Vt[v * 384 + t], s0);
        Wl24[(t / 6) * 24 + (t % 6) * 4 + 3] = s0;
        if (t < 128) {
            int ma = 256 + t;
            float s1 = 0.f;
#pragma unroll 8
            for (int v = 0; v < 128; ++v) s1 = fmaf(zl[v], Vt[v * 384 + ma], s1);
            Wl24[(ma / 6) * 24 + (ma % 6) * 4 + 3] = s1;
        }
    }
    if (first && t < 64) {
        const float* w = wcm + t * 131;
        float s = bcm[t];
#pragma unroll 8
        for (int i = 0; i < 128; ++i) s = fmaf(zl[i], w[i], s);
        s = fmaf(x[(size_t)b * NPTS * 10 + 0], w[128], s);
        s = fmaf(x[(size_t)b * NPTS * 10 + 1], w[129], s);
        s = fmaf(x[(size_t)b * NPTS * 10 + 2], w[130], s);
        C2l[t] = s;
    }
    __syncthreads();

    int idx = blk * 256 + t;
    const float* xp = x + (size_t)idx * 10;
    float x0 = xp[0], x1 = xp[1], x2 = xp[2];
    float rn = x0 * x0 + x1 * x1 + x2 * x2;
    float inv = 1.f / (sqrtf(rn) + 1e-8f);
    float c2[6];
    c2[0] = fmaxf(x2, 0.f) * inv; c2[1] = fmaxf(-x2, 0.f) * inv;
    c2[2] = fmaxf(x1, 0.f) * inv; c2[3] = fmaxf(-x1, 0.f) * inv;
    c2[4] = fmaxf(x0, 0.f) * inv; c2[5] = fmaxf(-x0, 0.f) * inv;
#pragma unroll
    for (int a = 0; a < 6; ++a) c2[a] *= c2[a];
    bool c0 = ((idx & 2047) == 0);
    float y[7];
#pragma unroll
    for (int k = 0; k < 7; ++k) y[k] = bf2[k];
#pragma unroll 4
    for (int m = 0; m < 64; ++m) {
        const float4* Wm = (const float4*)(Wl24 + m * 24);
        float h = 0.f;
#pragma unroll
        for (int a = 0; a < 6; ++a) {
            float4 wq = Wm[a];   // {T0,T1,T2,U}
            float ta = fmaf(x0, wq.x, fmaf(x1, wq.y, fmaf(x2, wq.z, wq.w)));
            h = fmaf(c2[a], ta, h);
        }
        if (c0) h = C2l[m];
        const float4* Pm = (const float4*)(Pl + m * 12);
        float4 p0 = Pm[0], p1 = Pm[1];
        float offv = Pl[m * 12 + 8];
        float r = fmaxf(fmaf(h, p1.w, offv), 0.f);
        y[0] = fmaf(r, p0.x, y[0]); y[1] = fmaf(r, p0.y, y[1]);
        y[2] = fmaf(r, p0.z, y[2]); y[3] = fmaf(r, p0.w, y[3]);
        y[4] = fmaf(r, p1.x, y[4]); y[5] = fmaf(r, p1.y, y[5]);
        y[6] = fmaf(r, p1.z, y[6]);
    }
#pragma unroll
    for (int k = 0; k < 7; ++k) yout[t * 7 + k] = 1.f / (1.f + __expf(-y[k]));
    __syncthreads();
    float* op = out + (size_t)blk * 1792;
    for (int g = t; g < 1792; g += 256) op[g] = yout[g];
}

// ---------------------------------------------------------------------------
extern "C" void kernel_launch(void* const* d_in, const int* in_sizes, int n_in,
                              void* d_out, int out_size, void* d_ws, size_t ws_size,
                              hipStream_t stream) {
    const float* x     = (const float*)d_in[0];
    // d_in[1]=Wc, d_in[2]=bc : dead code in reference
    const float* Wdir  = (const float*)d_in[3];
    const float* g1    = (const float*)d_in[4];
    const float* b1    = (const float*)d_in[5];
    const float* Wdir2 = (const float*)d_in[6];
    const float* g2    = (const float*)d_in[7];
    const float* b2    = (const float*)d_in[8];
    const float* Wf1   = (const float*)d_in[9];
    const float* bf1   = (const float*)d_in[10];
    const float* Wcm   = (const float*)d_in[11];
    const float* bcm   = (const float*)d_in[12];
    const float* Wdc   = (const float*)d_in[13];
    const float* Wm0   = (const float*)d_in[14];
    const float* g3    = (const float*)d_in[15];
    const float* b3    = (const float*)d_in[16];
    const float* Wf2   = (const float*)d_in[17];
    const float* bf2   = (const float*)d_in[18];
    float* ws  = (float*)d_ws;
    float* out = (float*)d_out;

    k_wa <<<262, 256, 0, stream>>>(x, Wm0, Wdc, bf1, ws);
    k_b1z<<<8,   256, 0, stream>>>(Wdir, g1, b1, Wdir2, g2, b2, Wf1, ws);
    k_c  <<<512, 256, 0, stream>>>(x, Wcm, bcm, ws);
    k_fin<<<1,   256, 0, stream>>>(g3, b3, ws);
    k_e  <<<512, 256, 0, stream>>>(x, Wcm, bcm, Wf2, bf2, ws, out);
}